// Round 10
// baseline (93.137 us; speedup 1.0000x reference)
//
#include <hip/hip_runtime.h>
#include <hip/hip_bf16.h>
#include <hip/hip_cooperative_groups.h>

namespace cg = cooperative_groups;

#define NNZ   104858
#define NB    1024
#define NIN   1024
#define NOUT  1024

typedef __bf16 bf16;
typedef bf16  bf16x8 __attribute__((ext_vector_type(8)));
typedef float f32x4  __attribute__((ext_vector_type(4)));

__device__ __forceinline__ void gload_lds16(const void* g, void* l) {
    __builtin_amdgcn_global_load_lds((const __attribute__((address_space(1))) void*)g,
                                     (__attribute__((address_space(3))) void*)l,
                                     16, 0, 0);
}

// ONE cooperative kernel, 256 blocks x 512 threads (1 block/CU, co-resident).
// Phase 1: zero Wd + convert x->bf16. Phase 2: densify (device-scope atomics).
// Phase 3: round-7-verified GEMM body (64x64 tile/block, in-block split-K=2,
// LDS-staged A via global_load_lds, reg-staged B w/ in-reg f32->bf16 convert,
// XOR-swizzled LDS both sides, single plain-store writer of d_out).
// grid.sync() = device-scope fence + barrier (cross-XCD safe per G16).
__global__ __launch_bounds__(512)
void k_fused(const float* __restrict__ x, const float* __restrict__ wts,
             const float* __restrict__ bias, const int* __restrict__ idx,
             float* __restrict__ Wd, bf16* __restrict__ xb,
             float* __restrict__ out) {
    __shared__ __align__(16) bf16 As[2][64 * 64];
    __shared__ __align__(16) bf16 Bs[2][64 * 64];
    __shared__ f32x4 red[4][64][4];

    cg::grid_group grid = cg::this_grid();
    const int gid = blockIdx.x * 512 + threadIdx.x;   // 0..131071

    // ---- phase 1: zero Wd (8 f32/thread) + convert x (8 elems/thread) ----
    {
        float4 z = {0.f, 0.f, 0.f, 0.f};
        float4* w4 = (float4*)Wd;
        w4[gid * 2]     = z;
        w4[gid * 2 + 1] = z;

        const int base = gid * 8;
        const float4* s4 = (const float4*)(x + base);
        float4 v0 = s4[0], v1 = s4[1];
        bf16x8 o;
        o[0] = (bf16)v0.x; o[1] = (bf16)v0.y; o[2] = (bf16)v0.z; o[3] = (bf16)v0.w;
        o[4] = (bf16)v1.x; o[5] = (bf16)v1.y; o[6] = (bf16)v1.z; o[7] = (bf16)v1.w;
        *(bf16x8*)(xb + base) = o;
    }
    grid.sync();

    // ---- phase 2: densify Wd[r][c] += w_k ----
    if (gid < NNZ) {
        int r = idx[gid] & (NOUT - 1);
        int c = idx[NNZ + gid] & (NIN - 1);
        atomicAdd(&Wd[r * NIN + c], wts[gid]);
    }
    grid.sync();

    // ---- phase 3: GEMM out = xb * bf16(Wd)^T + bias (round-7 body) ----
    const int b  = blockIdx.x;
    const int id = (b & 7) * 32 + (b >> 3);           // XCD-aware swizzle
    const int m0 = (id & 15) * 64, n0 = (id >> 4) * 64;

    const int t    = threadIdx.x;
    const int lane = t & 63;
    const int wv   = t >> 6;
    const int half = wv >> 2;
    const int w4i  = wv & 3, wr = w4i >> 1, wc = w4i & 1;
    const int fr   = lane & 15, fg = lane >> 4;

    const int th   = t & 255;
    const int srow = th >> 3;
    const int sg   = th & 7;
    const int brow = th >> 2;
    const int bq   = th & 3;

    f32x4 acc[2][2] = {};

    const float* wrow = Wd + (size_t)(n0 + brow) * NIN + half * 512;
    float4 bv0, bv1, bv2, bv3;
    {
        const float4* p = (const float4*)(wrow + bq * 16);
        bv0 = p[0]; bv1 = p[1]; bv2 = p[2]; bv3 = p[3];
    }

    for (int ks = 0; ks < 8; ++ks) {
        const int kbase = half * 512 + ks * 64;
        #pragma unroll
        for (int i = 0; i < 2; ++i) {
            int row = i * 32 + srow;
            int g2  = sg ^ (row & 7);
            gload_lds16(xb + (size_t)(m0 + row) * NIN + kbase + g2 * 8,
                        As[half] + row * 64 + sg * 8);
        }
        {
            bf16x8 o0, o1;
            o0[0] = (bf16)bv0.x; o0[1] = (bf16)bv0.y; o0[2] = (bf16)bv0.z; o0[3] = (bf16)bv0.w;
            o0[4] = (bf16)bv1.x; o0[5] = (bf16)bv1.y; o0[6] = (bf16)bv1.z; o0[7] = (bf16)bv1.w;
            o1[0] = (bf16)bv2.x; o1[1] = (bf16)bv2.y; o1[2] = (bf16)bv2.z; o1[3] = (bf16)bv2.w;
            o1[4] = (bf16)bv3.x; o1[5] = (bf16)bv3.y; o1[6] = (bf16)bv3.z; o1[7] = (bf16)bv3.w;
            int g0 = (bq * 2)     ^ (brow & 7);
            int g1 = (bq * 2 + 1) ^ (brow & 7);
            *(bf16x8*)(Bs[half] + brow * 64 + g0 * 8) = o0;
            *(bf16x8*)(Bs[half] + brow * 64 + g1 * 8) = o1;
        }
        __syncthreads();

        if (ks < 7) {
            const float4* p = (const float4*)(wrow + (ks + 1) * 64 + bq * 16);
            bv0 = p[0]; bv1 = p[1]; bv2 = p[2]; bv3 = p[3];
        }

        bf16x8 af[2][2], bfr[2][2];
        #pragma unroll
        for (int mi = 0; mi < 2; ++mi) {
            int row = wr * 32 + mi * 16 + fr;
            #pragma unroll
            for (int kk = 0; kk < 2; ++kk) {
                int gsw = (kk * 4 + fg) ^ (row & 7);
                af[mi][kk] = *(const bf16x8*)(As[half] + row * 64 + gsw * 8);
            }
        }
        #pragma unroll
        for (int ni = 0; ni < 2; ++ni) {
            int row = wc * 32 + ni * 16 + fr;
            #pragma unroll
            for (int kk = 0; kk < 2; ++kk) {
                int gsw = (kk * 4 + fg) ^ (row & 7);
                bfr[ni][kk] = *(const bf16x8*)(Bs[half] + row * 64 + gsw * 8);
            }
        }
        #pragma unroll
        for (int mi = 0; mi < 2; ++mi)
            #pragma unroll
            for (int ni = 0; ni < 2; ++ni)
                #pragma unroll
                for (int kk = 0; kk < 2; ++kk)
                    acc[mi][ni] = __builtin_amdgcn_mfma_f32_16x16x32_bf16(
                        af[mi][kk], bfr[ni][kk], acc[mi][ni], 0, 0, 0);
        __syncthreads();
    }

    if (half == 1) {
        #pragma unroll
        for (int mi = 0; mi < 2; ++mi)
            #pragma unroll
            for (int ni = 0; ni < 2; ++ni)
                red[w4i][lane][mi * 2 + ni] = acc[mi][ni];
    }
    __syncthreads();
    if (half == 0) {
        #pragma unroll
        for (int mi = 0; mi < 2; ++mi) {
            #pragma unroll
            for (int ni = 0; ni < 2; ++ni) {
                f32x4 p = red[w4i][lane][mi * 2 + ni];
                int row0 = m0 + wr * 32 + mi * 16 + fg * 4;
                int col  = n0 + wc * 32 + ni * 16 + fr;
                float bb = bias[col];
                #pragma unroll
                for (int j = 0; j < 4; ++j)
                    out[(size_t)(row0 + j) * NOUT + col] = acc[mi][ni][j] + p[j] + bb;
            }
        }
    }
}

// ---------------- launch ----------------
static inline size_t align256(size_t v) { return (v + 255) & ~(size_t)255; }

extern "C" void kernel_launch(void* const* d_in, const int* in_sizes, int n_in,
                              void* d_out, int out_size, void* d_ws, size_t ws_size,
                              hipStream_t stream) {
    const float* x    = (const float*)d_in[0];   // [NB][NIN]
    const float* wts  = (const float*)d_in[1];   // [NNZ]
    const float* bias = (const float*)d_in[2];   // [NOUT]
    const int*   idx  = (const int*)d_in[3];     // [2][NNZ] int32

    char* ws = (char*)d_ws;
    size_t off = 0;
    float* Wd = (float*)(ws + off); off = align256(off + (size_t)NOUT * NIN * 4);  // 4 MB
    bf16*  xb = (bf16*) (ws + off); off = align256(off + (size_t)NB * NIN * 2);    // 2 MB
    float* outp = (float*)d_out;

    void* args[] = {(void*)&x, (void*)&wts, (void*)&bias, (void*)&idx,
                    (void*)&Wd, (void*)&xb, (void*)&outp};
    hipLaunchCooperativeKernel((const void*)k_fused, dim3(256), dim3(512),
                               args, 0, stream);
}

// Round 11
// 29.711 us; speedup vs baseline: 3.1348x; 3.1348x over previous
//
#include <hip/hip_runtime.h>
#include <hip/hip_bf16.h>

#define NNZ   104858
#define NB    1024
#define NIN   1024
#define NOUT  1024

typedef __bf16 bf16;
typedef bf16  bf16x8 __attribute__((ext_vector_type(8)));
typedef float f32x4  __attribute__((ext_vector_type(4)));

// ---------------- pre: zero Wd | convert x->bf16 ----------------
__global__ __launch_bounds__(256)
void k_pre(const float* __restrict__ x, float* __restrict__ Wd,
           bf16* __restrict__ xb) {
    const int b = blockIdx.x, t = threadIdx.x;
    if (b < 512) {
        float4 z = {0.f, 0.f, 0.f, 0.f};
        float4* w4 = (float4*)Wd;
        int i = (b * 256 + t) * 2;
        w4[i] = z; w4[i + 1] = z;
    } else {
        const int base = ((b - 512) * 256 + t) * 8;
        const float4* s4 = (const float4*)(x + base);
        float4 v0 = s4[0], v1 = s4[1];
        bf16x8 o;
        o[0] = (bf16)v0.x; o[1] = (bf16)v0.y; o[2] = (bf16)v0.z; o[3] = (bf16)v0.w;
        o[4] = (bf16)v1.x; o[5] = (bf16)v1.y; o[6] = (bf16)v1.z; o[7] = (bf16)v1.w;
        *(bf16x8*)(xb + base) = o;
    }
}

// ---------------- densify: Wd[r][c] += w_k (f32 atomics; duplicates sum) ----
__global__ __launch_bounds__(256)
void k_densify(const int* __restrict__ idx, const float* __restrict__ w,
               float* __restrict__ Wd) {
    int k = blockIdx.x * 256 + threadIdx.x;
    if (k < NNZ) {
        int r = idx[k] & (NOUT - 1);
        int c = idx[NNZ + k] & (NIN - 1);
        atomicAdd(&Wd[r * NIN + c], w[k]);
    }
}

// ---------------- GEMM: out = x_bf16 * bf16(Wd)^T + bias ----------------
// Round-7 verified core (64x64 tile, 8 waves, in-block split-K=2, XOR-swizzled
// LDS both sides) with the K-loop re-scheduled as a TRUE double-buffer
// (T3-minimum recipe): per step, issue A gload_lds(k+1)->buf^1 and B reg
// loads(k+1) BEFORE computing step k from buf, convert+ds_write B(k+1) after
// compute, single barrier per step. Load latency hides under ds_read+MFMA
// (round 7 exposed the full round-trip every step: stage->sync->compute).
__device__ __forceinline__ void gload_lds16(const void* g, void* l) {
    __builtin_amdgcn_global_load_lds((const __attribute__((address_space(1))) void*)g,
                                     (__attribute__((address_space(3))) void*)l,
                                     16, 0, 0);
}

__global__ __launch_bounds__(512)
void k_gemm(const bf16* __restrict__ A, const float* __restrict__ Wd,
            const float* __restrict__ bias, float* __restrict__ out) {
    __shared__ __align__(16) bf16 As[2][2][64 * 64];   // [half][buf] 32 KB
    __shared__ __align__(16) bf16 Bs[2][2][64 * 64];   // 32 KB
    __shared__ f32x4 red[4][64][4];                    // 16 KB

    // XCD-aware swizzle: each XCD owns 2 n-panels (512 KB Wd) + xb (2 MB)
    const int b  = blockIdx.x;
    const int id = (b & 7) * 32 + (b >> 3);
    const int m0 = (id & 15) * 64, n0 = (id >> 4) * 64;

    const int t    = threadIdx.x;
    const int lane = t & 63;
    const int wv   = t >> 6;
    const int half = wv >> 2;
    const int w4i  = wv & 3, wr = w4i >> 1, wc = w4i & 1;
    const int fr   = lane & 15, fg = lane >> 4;

    const int th   = t & 255;
    const int srow = th >> 3;   // A staging: 0..31
    const int sg   = th & 7;
    const int brow = th >> 2;   // B staging: 0..63
    const int bq   = th & 3;

    f32x4 acc[2][2] = {};

    const float* wrow = Wd + (size_t)(n0 + brow) * NIN + half * 512;

    // ---- prologue: stage ks=0 into buf 0 ----
    {
        #pragma unroll
        for (int i = 0; i < 2; ++i) {
            int row = i * 32 + srow;
            int g2  = sg ^ (row & 7);
            gload_lds16(A + (size_t)(m0 + row) * NIN + half * 512 + g2 * 8,
                        As[half][0] + row * 64 + sg * 8);
        }
        const float4* p = (const float4*)(wrow + bq * 16);
        float4 v0 = p[0], v1 = p[1], v2 = p[2], v3 = p[3];
        bf16x8 o0, o1;
        o0[0] = (bf16)v0.x; o0[1] = (bf16)v0.y; o0[2] = (bf16)v0.z; o0[3] = (bf16)v0.w;
        o0[4] = (bf16)v1.x; o0[5] = (bf16)v1.y; o0[6] = (bf16)v1.z; o0[7] = (bf16)v1.w;
        o1[0] = (bf16)v2.x; o1[1] = (bf16)v2.y; o1[2] = (bf16)v2.z; o1[3] = (bf16)v2.w;
        o1[4] = (bf16)v3.x; o1[5] = (bf16)v3.y; o1[6] = (bf16)v3.z; o1[7] = (bf16)v3.w;
        int g0 = (bq * 2)     ^ (brow & 7);
        int g1 = (bq * 2 + 1) ^ (brow & 7);
        *(bf16x8*)(Bs[half][0] + brow * 64 + g0 * 8) = o0;
        *(bf16x8*)(Bs[half][0] + brow * 64 + g1 * 8) = o1;
    }
    __syncthreads();

    // ---- main loop: 8 K-steps, double-buffered ----
    for (int ks = 0; ks < 8; ++ks) {
        const int cur = ks & 1, nxt = cur ^ 1;

        // issue next-step loads FIRST (latency hides under compute below)
        float4 nv0, nv1, nv2, nv3;
        if (ks < 7) {
            const int kb = half * 512 + (ks + 1) * 64;
            #pragma unroll
            for (int i = 0; i < 2; ++i) {
                int row = i * 32 + srow;
                int g2  = sg ^ (row & 7);
                gload_lds16(A + (size_t)(m0 + row) * NIN + kb + g2 * 8,
                            As[half][nxt] + row * 64 + sg * 8);
            }
            const float4* p = (const float4*)(wrow + (ks + 1) * 64 + bq * 16);
            nv0 = p[0]; nv1 = p[1]; nv2 = p[2]; nv3 = p[3];
        }

        // compute step ks from buf cur
        bf16x8 af[2][2], bfr[2][2];
        #pragma unroll
        for (int mi = 0; mi < 2; ++mi) {
            int row = wr * 32 + mi * 16 + fr;
            #pragma unroll
            for (int kk = 0; kk < 2; ++kk) {
                int gsw = (kk * 4 + fg) ^ (row & 7);
                af[mi][kk] = *(const bf16x8*)(As[half][cur] + row * 64 + gsw * 8);
            }
        }
        #pragma unroll
        for (int ni = 0; ni < 2; ++ni) {
            int row = wc * 32 + ni * 16 + fr;
            #pragma unroll
            for (int kk = 0; kk < 2; ++kk) {
                int gsw = (kk * 4 + fg) ^ (row & 7);
                bfr[ni][kk] = *(const bf16x8*)(Bs[half][cur] + row * 64 + gsw * 8);
            }
        }
        #pragma unroll
        for (int mi = 0; mi < 2; ++mi)
            #pragma unroll
            for (int ni = 0; ni < 2; ++ni)
                #pragma unroll
                for (int kk = 0; kk < 2; ++kk)
                    acc[mi][ni] = __builtin_amdgcn_mfma_f32_16x16x32_bf16(
                        af[mi][kk], bfr[ni][kk], acc[mi][ni], 0, 0, 0);

        // write next B tile (waits on nv* arrival AFTER compute, not before)
        if (ks < 7) {
            bf16x8 o0, o1;
            o0[0] = (bf16)nv0.x; o0[1] = (bf16)nv0.y; o0[2] = (bf16)nv0.z; o0[3] = (bf16)nv0.w;
            o0[4] = (bf16)nv1.x; o0[5] = (bf16)nv1.y; o0[6] = (bf16)nv1.z; o0[7] = (bf16)nv1.w;
            o1[0] = (bf16)nv2.x; o1[1] = (bf16)nv2.y; o1[2] = (bf16)nv2.z; o1[3] = (bf16)nv2.w;
            o1[4] = (bf16)nv3.x; o1[5] = (bf16)nv3.y; o1[6] = (bf16)nv3.z; o1[7] = (bf16)nv3.w;
            int g0 = (bq * 2)     ^ (brow & 7);
            int g1 = (bq * 2 + 1) ^ (brow & 7);
            *(bf16x8*)(Bs[half][nxt] + brow * 64 + g0 * 8) = o0;
            *(bf16x8*)(Bs[half][nxt] + brow * 64 + g1 * 8) = o1;
        }
        __syncthreads();   // drains gload_lds(ks+1) + makes ds_writes visible
    }

    // ---- epilogue: cross-half reduce, single plain-store writer ----
    if (half == 1) {
        #pragma unroll
        for (int mi = 0; mi < 2; ++mi)
            #pragma unroll
            for (int ni = 0; ni < 2; ++ni)
                red[w4i][lane][mi * 2 + ni] = acc[mi][ni];
    }
    __syncthreads();
    if (half == 0) {
        #pragma unroll
        for (int mi = 0; mi < 2; ++mi) {
            #pragma unroll
            for (int ni = 0; ni < 2; ++ni) {
                f32x4 p = red[w4i][lane][mi * 2 + ni];
                int row0 = m0 + wr * 32 + mi * 16 + fg * 4;
                int col  = n0 + wc * 32 + ni * 16 + fr;
                float bb = bias[col];
                #pragma unroll
                for (int j = 0; j < 4; ++j)
                    out[(size_t)(row0 + j) * NOUT + col] = acc[mi][ni][j] + p[j] + bb;
            }
        }
    }
}

// ---------------- launch ----------------
static inline size_t align256(size_t v) { return (v + 255) & ~(size_t)255; }

extern "C" void kernel_launch(void* const* d_in, const int* in_sizes, int n_in,
                              void* d_out, int out_size, void* d_ws, size_t ws_size,
                              hipStream_t stream) {
    const float* x    = (const float*)d_in[0];   // [NB][NIN]
    const float* wts  = (const float*)d_in[1];   // [NNZ]
    const float* bias = (const float*)d_in[2];   // [NOUT]
    const int*   idx  = (const int*)d_in[3];     // [2][NNZ] int32

    char* ws = (char*)d_ws;
    size_t off = 0;
    float* Wd = (float*)(ws + off); off = align256(off + (size_t)NOUT * NIN * 4);  // 4 MB
    bf16*  xb = (bf16*) (ws + off); off = align256(off + (size_t)NB * NIN * 2);    // 2 MB

    const int nb_nnz = (NNZ + 255) / 256;

    k_pre<<<1024, 256, 0, stream>>>(x, Wd, xb);
    k_densify<<<nb_nnz, 256, 0, stream>>>(idx, wts, Wd);
    k_gemm<<<256, 512, 0, stream>>>(xb, Wd, bias, (float*)d_out);
}